// Round 9
// baseline (685.089 us; speedup 1.0000x reference)
//
#include <hip/hip_runtime.h>
#include <hip/hip_bf16.h>

#define BH 64
#define NKV 8192
#define NQ 2048
#define DIM 128
#define EPSV 1e-6f
#define KT 32
#define LDK 32    // bf16, XOR-swizzled, no pad
#define LDQ 136   // kvl row stride (bf16)

typedef __attribute__((ext_vector_type(8))) short bf16x8;
typedef __attribute__((ext_vector_type(4))) float f32x4;

__device__ __forceinline__ float phi_f(float x) { return x > 0.f ? x + 1.f : __expf(x); }

__device__ __forceinline__ ushort f2bf(float f) {
  unsigned u = __builtin_bit_cast(unsigned, f);
  u += 0x7FFFu + ((u >> 16) & 1u);   // round-to-nearest-even
  return (ushort)(u >> 16);
}
__device__ __forceinline__ float bf2f(ushort h) {
  unsigned u = ((unsigned)h) << 16;
  return __builtin_bit_cast(float, u);
}

// One fused kernel. Blocks [0, BH*NCH): phase A = partial KV/Z + last-block
// reduce per bh. Blocks [BH*NCH, +BH*16): phase B = k2 on a 128-row Q tile,
// Q preloaded to registers BEFORE spinning on ready[bh] (in-order dispatch
// places all A blocks first -> no deadlock; B overlaps A's tail).
template<int NCH>
__global__ __launch_bounds__(512, 4) void k_fused(
    const float* __restrict__ Qg, const float* __restrict__ Kg,
    const float* __restrict__ Vg, ushort* __restrict__ part,
    float* __restrict__ zpart, ushort* __restrict__ kvt,
    float* __restrict__ zred, unsigned* __restrict__ cnt,
    unsigned* __restrict__ ready, float* __restrict__ outg)
{
  __shared__ ushort smem[17664];   // A: ktl[2][4096]|vtl[2][4096]; B: kvl+zl
  __shared__ unsigned s_last;

  const int t = threadIdx.x;
  const int lane = t & 63;
  const int w = t >> 6;

  if (blockIdx.x < BH * NCH) {
    // ------------------------- phase A: KV partials -------------------------
    constexpr int ck = NKV / NCH;
    constexpr int ntile = ck / KT;
    const int wg = blockIdx.x;
    const int bh = wg / NCH;
    const int c  = wg - bh * NCH;
    const int isV = t >> 8;           // waves 0-3 stage K, 4-7 stage V
    const int ts = t & 255;
    const int p  = ts >> 4;           // row-pair 0..15
    const int db = (ts & 15) * 8;     // d base
    ushort* ktl0 = smem;
    ushort* vtl0 = smem + 8192;

    const long base = (long)bh * NKV * DIM + (long)c * ck * DIM;
    const float* Sp = (isV ? Vg : Kg) + base + (long)(2 * p) * DIM + db;

    f32x4 acc[8];
#pragma unroll
    for (int i = 0; i < 8; i++) acc[i] = (f32x4){0.f, 0.f, 0.f, 0.f};
    float zacc[8];
#pragma unroll
    for (int j = 0; j < 8; j++) zacc[j] = 0.f;

    const int kk = (lane >> 4) * 8;
    const int e  = w * 16 + (lane & 15);
    const int kke = kk ^ (((e >> 3) & 3) << 3);

    f32x4 stA[4], stB[4];
#define LOADT(dst, ti) do {                                            \
    const float* _s = Sp + (long)(ti) * (KT * DIM);                    \
    dst[0] = __builtin_nontemporal_load((const f32x4*)(_s));           \
    dst[1] = __builtin_nontemporal_load((const f32x4*)(_s + 4));       \
    dst[2] = __builtin_nontemporal_load((const f32x4*)(_s + DIM));     \
    dst[3] = __builtin_nontemporal_load((const f32x4*)(_s + DIM + 4)); \
  } while (0)

    LOADT(stA, 0);
    LOADT(stB, 1);

#define PROC(stX, ti, bufi) do {                                           \
    float r0[8] = {stX[0].x, stX[0].y, stX[0].z, stX[0].w,                 \
                   stX[1].x, stX[1].y, stX[1].z, stX[1].w};                \
    float r1[8] = {stX[2].x, stX[2].y, stX[2].z, stX[2].w,                 \
                   stX[3].x, stX[3].y, stX[3].z, stX[3].w};                \
    unsigned pk[8];                                                        \
    if (isV == 0) {                                                        \
      _Pragma("unroll")                                                    \
      for (int j = 0; j < 8; j++) {                                        \
        ushort a = f2bf(phi_f(r0[j]));                                     \
        ushort b = f2bf(phi_f(r1[j]));                                     \
        zacc[j] += bf2f(a) + bf2f(b);                                      \
        pk[j] = (unsigned)a | ((unsigned)b << 16);                         \
      }                                                                    \
    } else {                                                               \
      _Pragma("unroll")                                                    \
      for (int j = 0; j < 8; j++) {                                        \
        ushort a = f2bf(r0[j]);                                            \
        ushort b = f2bf(r1[j]);                                            \
        pk[j] = (unsigned)a | ((unsigned)b << 16);                         \
      }                                                                    \
    }                                                                      \
    if ((ti) + 2 < ntile) LOADT(stX, (ti) + 2);                            \
    ushort* dst = (isV ? vtl0 : ktl0) + (bufi) * 4096;                     \
    _Pragma("unroll")                                                      \
    for (int j = 0; j < 8; j++) {                                          \
      int row = db + j;                                                    \
      int col = (2 * p) ^ (((row >> 3) & 3) << 3);                         \
      *(unsigned*)&dst[row * LDK + col] = pk[j];                           \
    }                                                                      \
    __syncthreads();                                                       \
    bf16x8 bfr = *(const bf16x8*)&vtl0[(bufi) * 4096 + e * LDK + kke];     \
    _Pragma("unroll")                                                      \
    for (int dt = 0; dt < 8; dt++) {                                       \
      int dd = dt * 16 + (lane & 15);                                      \
      int kkd = kk ^ (((dd >> 3) & 3) << 3);                               \
      bf16x8 afr = *(const bf16x8*)&ktl0[(bufi) * 4096 + dd * LDK + kkd];  \
      acc[dt] = __builtin_amdgcn_mfma_f32_16x16x32_bf16(afr, bfr, acc[dt], 0, 0, 0); \
    }                                                                      \
  } while (0)

    for (int ti = 0; ti < ntile; ti += 2) {
      PROC(stA, ti, 0);
      PROC(stB, ti + 1, 1);
    }

    // partial KV transposed [e][d], bf16
    ushort* pp = part + (long)wg * (DIM * DIM);
#pragma unroll
    for (int dt = 0; dt < 8; dt++) {
      int d0 = dt * 16 + (lane >> 4) * 4;
      ushort o[4];
#pragma unroll
      for (int r = 0; r < 4; r++) o[r] = f2bf(acc[dt][r]);
      *(uint2*)&pp[(long)e * DIM + d0] = *(uint2*)o;
    }
    // Z partials: per-wave slices (waves 0-3 only)
    if (isV == 0) {
      float zr[8];
#pragma unroll
      for (int j = 0; j < 8; j++) {
        float z = zacc[j];
        z += __shfl_xor(z, 16, 64);
        z += __shfl_xor(z, 32, 64);
        zr[j] = z;
      }
      if ((lane & 48) == 0) {
        float* zp = zpart + ((long)wg * 4 + w) * DIM + (lane & 15) * 8;
#pragma unroll
        for (int j = 0; j < 8; j++) zp[j] = zr[j];
      }
    }
    __syncthreads();
    if (t == 0) {
      __threadfence();                       // release: flush partials to L3
      unsigned old = atomicAdd(&cnt[bh], 1u);
      s_last = (old == (unsigned)(NCH - 1)) ? 1u : 0u;
    }
    __syncthreads();
    if (s_last) {
      __threadfence();                       // acquire: invalidate stale L2
      const long pbase = (long)bh * NCH * (DIM * DIM);
#pragma unroll
      for (int i = 0; i < 4; i++) {
        int u4 = t + i * 512;                // 0..2047 uint4
        long off = pbase + (long)u4 * 8;
        float s[8] = {0.f, 0.f, 0.f, 0.f, 0.f, 0.f, 0.f, 0.f};
#pragma unroll
        for (int cc = 0; cc < NCH; cc++) {
          uint4 v = *(const uint4*)&part[off + (long)cc * (DIM * DIM)];
          unsigned ws_[4] = {v.x, v.y, v.z, v.w};
#pragma unroll
          for (int h = 0; h < 4; h++) {
            s[2 * h]     += bf2f((ushort)(ws_[h] & 0xFFFFu));
            s[2 * h + 1] += bf2f((ushort)(ws_[h] >> 16));
          }
        }
        unsigned o[4];
#pragma unroll
        for (int h = 0; h < 4; h++)
          o[h] = (unsigned)f2bf(s[2 * h]) | ((unsigned)f2bf(s[2 * h + 1]) << 16);
        *(uint4*)&kvt[(long)bh * (DIM * DIM) + (long)u4 * 8] =
            make_uint4(o[0], o[1], o[2], o[3]);
      }
      if (t < DIM) {
        float s = 0.f;
#pragma unroll
        for (int cc = 0; cc < NCH; cc++)
#pragma unroll
          for (int wv = 0; wv < 4; wv++)
            s += zpart[(((long)bh * NCH + cc) * 4 + wv) * DIM + t];
        zred[(long)bh * DIM + t] = s;
      }
      __syncthreads();
      if (t == 0) {
        __threadfence();                     // release kvt/zred
        atomicExch(&ready[bh], 1u);
      }
    }
  } else {
    // --------------------- phase B: out = num/den -------------------------
    const int idx = blockIdx.x - BH * NCH;
    const int bh = idx >> 4;
    const int q0 = (idx & 15) * 128;
    const int g = lane >> 4;                 // 0..3
    const int kk = g * 8;
    const int qr = lane & 15;
    ushort* kvl = smem;                      // [128][LDQ]
    float* zl = (float*)(smem + 17408);      // 128 f32

    // 1. preload Q tile to registers (overlaps A's tail while we spin)
    const float* Qp = Qg + ((long)bh * NQ + q0 + w * 16 + qr) * DIM + kk;
    f32x4 qv[8];
#pragma unroll
    for (int d0b = 0; d0b < 4; d0b++) {
      qv[2 * d0b]     = *(const f32x4*)(Qp + d0b * 32);
      qv[2 * d0b + 1] = *(const f32x4*)(Qp + d0b * 32 + 4);
    }
    // 2. phi -> bf16 A-fragments
    bf16x8 aq[4];
#pragma unroll
    for (int d0b = 0; d0b < 4; d0b++) {
      ushort h[8];
#pragma unroll
      for (int j = 0; j < 8; j++) {
        float x = (j < 4) ? qv[2 * d0b][j] : qv[2 * d0b + 1][j - 4];
        h[j] = f2bf(phi_f(x));
      }
      aq[d0b] = *(bf16x8*)h;
    }
    // 3. wait for this bh's KV cache
    if (t == 0) {
      while (atomicAdd(&ready[bh], 0u) == 0u) __builtin_amdgcn_s_sleep(2);
    }
    __syncthreads();
    __threadfence();                         // acquire: invalidate stale L2
    // 4. stage kvt -> LDS, Z -> LDS
    const ushort* kp = kvt + (long)bh * (DIM * DIM);
#pragma unroll
    for (int i = 0; i < 4; i++) {
      int i8 = t + i * 512;
      int row = i8 >> 4;
      int c8 = i8 & 15;
      *(uint4*)&kvl[row * LDQ + c8 * 8] = *(const uint4*)(kp + row * DIM + c8 * 8);
    }
    if (t < DIM) zl[t] = zred[(long)bh * DIM + t];
    __syncthreads();
    // 5. denominator per q-row
    float den = 0.f;
#pragma unroll
    for (int d0b = 0; d0b < 4; d0b++)
#pragma unroll
      for (int j = 0; j < 8; j++)
        den += bf2f((ushort)aq[d0b][j]) * zl[d0b * 32 + kk + j];
    den += __shfl_xor(den, 16, 64);
    den += __shfl_xor(den, 32, 64);
    float invd = 1.f / (den + EPSV);
    // 6. numerator MFMA
    f32x4 acc[8];
#pragma unroll
    for (int et = 0; et < 8; et++) acc[et] = (f32x4){0.f, 0.f, 0.f, 0.f};
#pragma unroll
    for (int d0b = 0; d0b < 4; d0b++) {
#pragma unroll
      for (int et = 0; et < 8; et++) {
        bf16x8 bfr = *(const bf16x8*)&kvl[(et * 16 + qr) * LDQ + d0b * 32 + kk];
        acc[et] = __builtin_amdgcn_mfma_f32_16x16x32_bf16(aq[d0b], bfr, acc[et], 0, 0, 0);
      }
    }
    // 7. epilogue
    float* op = outg + ((long)bh * NQ + q0 + w * 16) * DIM;
#pragma unroll
    for (int et = 0; et < 8; et++) {
      int e2 = et * 16 + qr;
#pragma unroll
      for (int r = 0; r < 4; r++) {
        float iv = __shfl(invd, g * 4 + r, 64);
        op[(long)(g * 4 + r) * DIM + e2] = acc[et][r] * iv;
      }
    }
  }
}

extern "C" void kernel_launch(void* const* d_in, const int* in_sizes, int n_in,
                              void* d_out, int out_size, void* d_ws, size_t ws_size,
                              hipStream_t stream) {
  const float* Q  = (const float*)d_in[0];
  const float* Km = (const float*)d_in[1];
  const float* Vm = (const float*)d_in[2];
  float* out = (float*)d_out;

  char* ws = (char*)d_ws;
  ushort* kvt = (ushort*)ws;                                    // 2 MB
  float* zred = (float*)(ws + (size_t)BH * DIM * DIM * 2);      // 32 KB
  size_t flagoff = (size_t)BH * DIM * DIM * 2 + (size_t)BH * DIM * 4;
  unsigned* cnt   = (unsigned*)(ws + flagoff);                  // 256 B
  unsigned* ready = cnt + BH;                                   // 256 B
  size_t fixed = flagoff + 512;

  int nch = 16;
  {
    size_t need = fixed + (size_t)BH * nch * DIM * DIM * 2
                + (size_t)BH * nch * 4 * DIM * 4;
    if (need > ws_size) nch = 8;
  }
  ushort* partb = (ushort*)(ws + fixed);
  float* zpart = (float*)(ws + fixed + (size_t)BH * nch * DIM * DIM * 2);

  hipMemsetAsync(cnt, 0, 512, stream);

  dim3 grid(BH * nch + BH * 16);
  if (nch == 16)
    k_fused<16><<<grid, 512, 0, stream>>>(Q, Km, Vm, partb, zpart, kvt, zred, cnt, ready, out);
  else
    k_fused<8><<<grid, 512, 0, stream>>>(Q, Km, Vm, partb, zpart, kvt, zred, cnt, ready, out);
}

// Round 10
// 156.701 us; speedup vs baseline: 4.3719x; 4.3719x over previous
//
#include <hip/hip_runtime.h>
#include <hip/hip_bf16.h>

#define BH 64
#define NKV 8192
#define NQ 2048
#define DIM 128
#define EPSV 1e-6f

typedef __attribute__((ext_vector_type(8))) short bf16x8;
typedef __attribute__((ext_vector_type(4))) float f32x4;
typedef __attribute__((ext_vector_type(2))) unsigned u32x2;
typedef __attribute__((ext_vector_type(4))) unsigned u32x4;

__device__ __forceinline__ float phi_f(float x) { return x > 0.f ? x + 1.f : __expf(x); }

__device__ __forceinline__ ushort f2bf(float f) {
  unsigned u = __builtin_bit_cast(unsigned, f);
  u += 0x7FFFu + ((u >> 16) & 1u);   // round-to-nearest-even
  return (ushort)(u >> 16);
}
__device__ __forceinline__ float bf2f(ushort h) {
  unsigned u = ((unsigned)h) << 16;
  return __builtin_bit_cast(float, u);
}

// ---------------- Kernel 1: partial KV = phi(K)^T V and partial Z ------------
// r8 structure (155us known-good): 512 thr, waves 0-3 K / 4-7 V, depth-2
// register prefetch, dbuf bf16 LDS, 1 barrier/tile, nt K/V loads.
// NEW: nt stores for partials (don't pollute L3 -> more K/V hits).
#define KT 32
#define LDK 32

__global__ __launch_bounds__(512, 4) void k1_kv(
    const float* __restrict__ Kg, const float* __restrict__ Vg,
    ushort* __restrict__ part, float* __restrict__ zpart, int nch, int ck)
{
  __shared__ ushort ktl[2][DIM * LDK];
  __shared__ ushort vtl[2][DIM * LDK];

  const int wg = blockIdx.x;
  const int bh = wg / nch;
  const int c  = wg - bh * nch;
  const int t  = threadIdx.x;
  const int lane = t & 63;
  const int w  = t >> 6;            // wave 0..7 -> e-tile = w*16
  const int isV = t >> 8;           // 0: stage K, 1: stage V (wave-uniform)
  const int ts = t & 255;
  const int p  = ts >> 4;           // row-pair 0..15
  const int db = (ts & 15) * 8;     // d base for staging

  const long base = (long)bh * NKV * DIM + (long)c * ck * DIM;
  const float* Sp = (isV ? Vg : Kg) + base + (long)(2 * p) * DIM + db;

  f32x4 acc[8];
#pragma unroll
  for (int i = 0; i < 8; i++) acc[i] = (f32x4){0.f, 0.f, 0.f, 0.f};
  float zacc[8];
#pragma unroll
  for (int j = 0; j < 8; j++) zacc[j] = 0.f;

  const int kk = (lane >> 4) * 8;
  const int e  = w * 16 + (lane & 15);
  const int kke = kk ^ (((e >> 3) & 3) << 3);

  const int ntile = ck / KT;

  f32x4 stA[4], stB[4];
#define LOADT(dst, ti) do {                                            \
    const float* _s = Sp + (long)(ti) * (KT * DIM);                    \
    dst[0] = __builtin_nontemporal_load((const f32x4*)(_s));           \
    dst[1] = __builtin_nontemporal_load((const f32x4*)(_s + 4));       \
    dst[2] = __builtin_nontemporal_load((const f32x4*)(_s + DIM));     \
    dst[3] = __builtin_nontemporal_load((const f32x4*)(_s + DIM + 4)); \
  } while (0)

  LOADT(stA, 0);
  LOADT(stB, 1);

#define PROC(stX, ti, bufi) do {                                           \
    float r0[8] = {stX[0].x, stX[0].y, stX[0].z, stX[0].w,                 \
                   stX[1].x, stX[1].y, stX[1].z, stX[1].w};                \
    float r1[8] = {stX[2].x, stX[2].y, stX[2].z, stX[2].w,                 \
                   stX[3].x, stX[3].y, stX[3].z, stX[3].w};                \
    unsigned pk[8];                                                        \
    if (isV == 0) {                                                        \
      _Pragma("unroll")                                                    \
      for (int j = 0; j < 8; j++) {                                        \
        ushort a = f2bf(phi_f(r0[j]));                                     \
        ushort b = f2bf(phi_f(r1[j]));                                     \
        zacc[j] += bf2f(a) + bf2f(b);                                      \
        pk[j] = (unsigned)a | ((unsigned)b << 16);                         \
      }                                                                    \
    } else {                                                               \
      _Pragma("unroll")                                                    \
      for (int j = 0; j < 8; j++) {                                        \
        ushort a = f2bf(r0[j]);                                            \
        ushort b = f2bf(r1[j]);                                            \
        pk[j] = (unsigned)a | ((unsigned)b << 16);                         \
      }                                                                    \
    }                                                                      \
    if ((ti) + 2 < ntile) LOADT(stX, (ti) + 2);                            \
    ushort* dst = isV ? vtl[bufi] : ktl[bufi];                             \
    _Pragma("unroll")                                                      \
    for (int j = 0; j < 8; j++) {                                          \
      int row = db + j;                                                    \
      int col = (2 * p) ^ (((row >> 3) & 3) << 3);                         \
      *(unsigned*)&dst[row * LDK + col] = pk[j];                           \
    }                                                                      \
    __syncthreads();                                                       \
    bf16x8 bfr = *(const bf16x8*)&vtl[bufi][e * LDK + kke];                \
    _Pragma("unroll")                                                      \
    for (int dt = 0; dt < 8; dt++) {                                       \
      int dd = dt * 16 + (lane & 15);                                      \
      int kkd = kk ^ (((dd >> 3) & 3) << 3);                               \
      bf16x8 afr = *(const bf16x8*)&ktl[bufi][dd * LDK + kkd];             \
      acc[dt] = __builtin_amdgcn_mfma_f32_16x16x32_bf16(afr, bfr, acc[dt], 0, 0, 0); \
    }                                                                      \
  } while (0)

  for (int ti = 0; ti < ntile; ti += 2) {
    PROC(stA, ti, 0);
    PROC(stB, ti + 1, 1);
  }

  // write partial KV transposed [e][d], bf16, nt (keep L3 for K/V)
  ushort* pp = part + (long)wg * (DIM * DIM);
#pragma unroll
  for (int dt = 0; dt < 8; dt++) {
    int d0 = dt * 16 + (lane >> 4) * 4;
    ushort o[4];
#pragma unroll
    for (int r = 0; r < 4; r++) o[r] = f2bf(acc[dt][r]);
    __builtin_nontemporal_store(*(u32x2*)o, (u32x2*)&pp[(long)e * DIM + d0]);
  }

  // Z: intra-wave reduce, per-wave slice to zpart (waves 0-3 only)
  if (isV == 0) {
    float zr[8];
#pragma unroll
    for (int j = 0; j < 8; j++) {
      float z = zacc[j];
      z += __shfl_xor(z, 16, 64);
      z += __shfl_xor(z, 32, 64);
      zr[j] = z;
    }
    if ((lane & 48) == 0) {   // lanes 0..15
      float* zp = zpart + ((long)wg * 4 + w) * DIM + (lane & 15) * 8;
#pragma unroll
      for (int j = 0; j < 8; j++) __builtin_nontemporal_store(zr[j], zp + j);
    }
  }
}

// ------------- Reduce: sum bf16 partials (already [e][d]); emit kvt, Z ------
template<int NCH>
__global__ __launch_bounds__(256) void k_red(
    const ushort* __restrict__ part, const float* __restrict__ zpart,
    ushort* __restrict__ kvt, float* __restrict__ zout)
{
  const int bh = blockIdx.x >> 2;
  const int quad = blockIdx.x & 3;
  const int t = threadIdx.x;
  const long pbase = (long)bh * NCH * (DIM * DIM);

#pragma unroll
  for (int i = 0; i < 2; i++) {
    int u4 = quad * 512 + t + i * 256;
    long off = pbase + (long)u4 * 8;
    float s[8] = {0.f, 0.f, 0.f, 0.f, 0.f, 0.f, 0.f, 0.f};
#pragma unroll
    for (int cc = 0; cc < NCH; cc++) {
      u32x4 v = __builtin_nontemporal_load(
          (const u32x4*)&part[off + (long)cc * (DIM * DIM)]);
#pragma unroll
      for (int h = 0; h < 4; h++) {
        s[2 * h]     += bf2f((ushort)(v[h] & 0xFFFFu));
        s[2 * h + 1] += bf2f((ushort)(v[h] >> 16));
      }
    }
    unsigned o[4];
#pragma unroll
    for (int h = 0; h < 4; h++)
      o[h] = (unsigned)f2bf(s[2 * h]) | ((unsigned)f2bf(s[2 * h + 1]) << 16);
    *(uint4*)&kvt[(long)bh * (DIM * DIM) + (long)u4 * 8] =
        make_uint4(o[0], o[1], o[2], o[3]);
  }

  if (quad == 0 && t < DIM) {
    float s = 0.f;
#pragma unroll
    for (int cc = 0; cc < NCH; cc++)
#pragma unroll
      for (int wv = 0; wv < 4; wv++)
        s += zpart[(((long)bh * NCH + cc) * 4 + wv) * DIM + t];
    zout[(long)bh * DIM + t] = s;
  }
}

// --------- Kernel 2: out = (phi(Q) KV) / (phi(Q)·Z + eps) -------------------
#define QB 64
#define LDQ 136   // 128 + 8 pad

__global__ __launch_bounds__(256) void k2_fwd(
    const float* __restrict__ Qg, const ushort* __restrict__ kvt,
    const float* __restrict__ zg, float* __restrict__ outg)
{
  __shared__ ushort ql[QB * LDQ];
  __shared__ ushort kvl[DIM * LDQ];
  __shared__ float zl[DIM];
  __shared__ float dpart[4][QB];
  __shared__ float invd[QB];

  const int bid = blockIdx.x;
  const int bh = bid >> 5;
  const int q0 = (bid & 31) * QB;
  const int t = threadIdx.x;
  const int lane = t & 63;
  const int w = t >> 6;

  if (t < DIM) zl[t] = zg[(long)bh * DIM + t];

  const float* Qp = Qg + ((long)bh * NQ + q0) * DIM;
#pragma unroll
  for (int i = 0; i < 8; i++) {
    int idx4 = t + i * 256;
    int row = idx4 >> 5;
    int c4 = idx4 & 31;
    float4 v = *(const float4*)(Qp + (long)row * DIM + c4 * 4);
    ushort a = f2bf(phi_f(v.x)), b = f2bf(phi_f(v.y));
    ushort cq = f2bf(phi_f(v.z)), dq = f2bf(phi_f(v.w));
    uint2 pk;
    pk.x = (unsigned)a | ((unsigned)b << 16);
    pk.y = (unsigned)cq | ((unsigned)dq << 16);
    *(uint2*)&ql[row * LDQ + c4 * 4] = pk;
  }
  const ushort* kp = kvt + (long)bh * (DIM * DIM);
#pragma unroll
  for (int i = 0; i < 8; i++) {
    int idx8 = t + i * 256;
    int row = idx8 >> 4;
    int c8 = idx8 & 15;
    uint4 vv = *(const uint4*)(kp + row * DIM + c8 * 8);
    *(uint4*)&kvl[row * LDQ + c8 * 8] = vv;
  }
  __syncthreads();

  {
    int row = t & (QB - 1);
    int q4 = t >> 6;
    float s = 0.f;
#pragma unroll
    for (int i = 0; i < 4; i++) {
      int d0 = q4 * 32 + i * 8;
      bf16x8 qv = *(const bf16x8*)&ql[row * LDQ + d0];
#pragma unroll
      for (int j = 0; j < 8; j++)
        s += bf2f((ushort)qv[j]) * zl[d0 + j];
    }
    dpart[q4][row] = s;
  }
  __syncthreads();
  if (t < QB) {
    float den = dpart[0][t] + dpart[1][t] + dpart[2][t] + dpart[3][t] + EPSV;
    invd[t] = 1.f / den;
  }
  __syncthreads();

  const int kk = (lane >> 4) * 8;
  const int qrow = w * 16 + (lane & 15);
  f32x4 acc[8];
#pragma unroll
  for (int et = 0; et < 8; et++) acc[et] = (f32x4){0.f, 0.f, 0.f, 0.f};

#pragma unroll
  for (int d0 = 0; d0 < DIM; d0 += 32) {
    bf16x8 afr = *(const bf16x8*)&ql[qrow * LDQ + d0 + kk];
#pragma unroll
    for (int et = 0; et < 8; et++) {
      int e = et * 16 + (lane & 15);
      bf16x8 bfr = *(const bf16x8*)&kvl[e * LDQ + d0 + kk];
      acc[et] = __builtin_amdgcn_mfma_f32_16x16x32_bf16(afr, bfr, acc[et], 0, 0, 0);
    }
  }

  // epilogue: scale by 1/den, nt store (out never re-read; keep L3 clean)
  float* op = outg + ((long)bh * NQ + q0) * DIM;
#pragma unroll
  for (int et = 0; et < 8; et++) {
    int e = et * 16 + (lane & 15);
    int r0 = w * 16 + (lane >> 4) * 4;
#pragma unroll
    for (int r = 0; r < 4; r++) {
      float val = acc[et][r] * invd[r0 + r];
      __builtin_nontemporal_store(val, op + (long)(r0 + r) * DIM + e);
    }
  }
}

extern "C" void kernel_launch(void* const* d_in, const int* in_sizes, int n_in,
                              void* d_out, int out_size, void* d_ws, size_t ws_size,
                              hipStream_t stream) {
  const float* Q  = (const float*)d_in[0];
  const float* Km = (const float*)d_in[1];
  const float* Vm = (const float*)d_in[2];
  float* out = (float*)d_out;

  char* ws = (char*)d_ws;
  ushort* kvt = (ushort*)ws;                                    // 2 MB
  float* zred = (float*)(ws + (size_t)BH * DIM * DIM * 2);      // 32 KB
  size_t fixed = (size_t)BH * DIM * DIM * 2 + (size_t)BH * DIM * 4;

  int nch = 16;
  while (nch > 1) {
    size_t need = fixed + (size_t)BH * nch * DIM * DIM * 2
                + (size_t)BH * nch * 4 * DIM * 4;
    if (need <= ws_size) break;
    nch >>= 1;
  }
  ushort* partb = (ushort*)(ws + fixed);
  float* zpart = (float*)(ws + fixed + (size_t)BH * nch * DIM * DIM * 2);
  int ck = NKV / nch;

  k1_kv<<<BH * nch, 512, 0, stream>>>(Km, Vm, partb, zpart, nch, ck);

  dim3 rg(BH * 4);
  switch (nch) {
    case 16: k_red<16><<<rg, 256, 0, stream>>>(partb, zpart, kvt, zred); break;
    case 8:  k_red<8> <<<rg, 256, 0, stream>>>(partb, zpart, kvt, zred); break;
    case 4:  k_red<4> <<<rg, 256, 0, stream>>>(partb, zpart, kvt, zred); break;
    case 2:  k_red<2> <<<rg, 256, 0, stream>>>(partb, zpart, kvt, zred); break;
    default: k_red<1> <<<rg, 256, 0, stream>>>(partb, zpart, kvt, zred); break;
  }

  k2_fwd<<<BH * 32, 256, 0, stream>>>(Q, kvt, zred, out);
}